// Round 2
// baseline (2545.747 us; speedup 1.0000x reference)
//
#include <hip/hip_runtime.h>
#include <hip/hip_bf16.h>

// Shapes (fixed by the problem)
#define CC    128          // channels
#define Hh    128
#define Ww    128
#define HWp   16384        // H*W
#define BTOT  16           // batches

// Attention-kernel LDS layout:
//   Qs   : 128x128 fp32, XOR-swizzled in 16B blocks  -> 65536 B
//   Ar,Ac: 128xAST bf16 (linear)                     -> 2*33792 B
#define AST   132
#define SMEM_ATTN (65536 + 2 * (CC * AST * 2))   // 133120 B

// -------- Q LDS swizzle helpers (float index into Qs) --------
// float4-block (r, c4) stored at column-block c4 ^ ((r>>3)&7).
// Makes both row-contiguous float4 reads and 8-row-strided float4 reads
// conflict-free (<=2-way).
__device__ __forceinline__ int qoff4(int r, int c4) {
    return (r << 7) + ((c4 ^ ((r >> 3) & 7)) << 2);
}
__device__ __forceinline__ int qoff1(int r, int c) {
    return (r << 7) + ((((c >> 2) ^ ((r >> 3) & 7)) << 2) | (c & 3));
}

// ================= Kernel 1: qkv = c_w @ concat(x1,x2) + c_b =================
// One thread per pixel; 128-channel input column lives in VGPRs; weights are
// wave-uniform -> scalar (s_load) reads.
__global__ __launch_bounds__(256, 2)
void k_qkv(const float* __restrict__ x1, const float* __restrict__ x2,
           const float* __restrict__ w, const float* __restrict__ bias,
           float* __restrict__ out, int npix)
{
    int p = blockIdx.x * 256 + threadIdx.x;
    if (p >= npix) return;
    int b = p >> 14;            // p / HWp  (chunk-local batch)
    int s = p & (HWp - 1);
    const float* p1 = x1 + (size_t)b * 64 * HWp + s;
    const float* p2 = x2 + (size_t)b * 64 * HWp + s;
    float xr[CC];
#pragma unroll
    for (int c = 0; c < 64; ++c) xr[c] = p1[(size_t)c * HWp];
#pragma unroll
    for (int c = 0; c < 64; ++c) xr[64 + c] = p2[(size_t)c * HWp];
    float* po = out + (size_t)b * CC * HWp + s;
    const float4* w4 = (const float4*)w;
    for (int o = 0; o < CC; ++o) {
        float acc = bias[o];
#pragma unroll
        for (int k = 0; k < 32; ++k) {
            float4 wv = w4[o * 32 + k];
            acc = fmaf(wv.x, xr[4 * k + 0], acc);
            acc = fmaf(wv.y, xr[4 * k + 1], acc);
            acc = fmaf(wv.z, xr[4 * k + 2], acc);
            acc = fmaf(wv.w, xr[4 * k + 3], acc);
        }
        po[(size_t)o * HWp] = acc;
    }
}

// ================= Kernel 3: z = sc_w @ v + sc_b (plane-major input) =========
__global__ __launch_bounds__(256, 2)
void k_c1(const float* __restrict__ in, const float* __restrict__ w,
          const float* __restrict__ bias, float* __restrict__ out, int npix)
{
    int p = blockIdx.x * 256 + threadIdx.x;
    if (p >= npix) return;
    int b = p >> 14;
    int s = p & (HWp - 1);
    const float* pin = in + (size_t)b * CC * HWp + s;
    float xr[CC];
#pragma unroll
    for (int c = 0; c < CC; ++c) xr[c] = pin[(size_t)c * HWp];
    float* po = out + (size_t)b * CC * HWp + s;
    const float4* w4 = (const float4*)w;
    for (int o = 0; o < CC; ++o) {
        float acc = bias[o];
#pragma unroll
        for (int k = 0; k < 32; ++k) {
            float4 wv = w4[o * 32 + k];
            acc = fmaf(wv.x, xr[4 * k + 0], acc);
            acc = fmaf(wv.y, xr[4 * k + 1], acc);
            acc = fmaf(wv.z, xr[4 * k + 2], acc);
            acc = fmaf(wv.w, xr[4 * k + 3], acc);
        }
        po[(size_t)o * HWp] = acc;
    }
}

// ================= Kernel 2: per-(b,c) dual axial attention ==================
// 512 threads: waves 0-3 (grp 0) do row attention, waves 4-7 (grp 1) column.
// Each of the 256 threads per group owns an 8x8 register tile of the 128x128
// score/output matrix. Softmax entirely in registers via 16-lane shfl_xor.
__global__ __launch_bounds__(512, 2)
void k_attn(const float* __restrict__ qkv, float* __restrict__ xrow,
            float* __restrict__ xcol)
{
    extern __shared__ float smem[];
    float* Qs = smem;                                        // swizzled 128x128
    __hip_bfloat16* Ar = (__hip_bfloat16*)(smem + CC * 128); // [128][AST]
    __hip_bfloat16* Ac = Ar + CC * AST;

    const int tid = threadIdx.x;
    const size_t plane = blockIdx.x;
    const float* Qg = qkv + plane * (size_t)HWp;

    // ---- load Q (swizzled) ----
    const float4* Qg4 = (const float4*)Qg;
    for (int e = tid; e < HWp / 4; e += 512) {
        int r = e >> 5, c4 = e & 31;
        *(float4*)&Qs[qoff4(r, c4)] = Qg4[e];
    }
    __syncthreads();

    const int grp = tid >> 8;        // 0 = row-attn, 1 = col-attn
    const int t   = tid & 255;
    const int ti  = t >> 4;          // 0..15
    const int tj  = t & 15;          // 0..15
    const int ra  = ti * 8;
    const int rb  = tj * 8;
    const float scale = 0.08838834764831845f;  // 128^-0.5

    float acc[8][8];
#pragma unroll
    for (int a = 0; a < 8; ++a)
#pragma unroll
        for (int b2 = 0; b2 < 8; ++b2) acc[a][b2] = 0.f;

    if (grp == 0) {
        // S_row[h][g] = sum_w Q[h][w] * Q[g][w]; h = ra+a, g = rb+b
        for (int k4 = 0; k4 < 32; ++k4) {
            float4 qa[8], qb[8];
#pragma unroll
            for (int a = 0; a < 8; ++a) qa[a] = *(const float4*)&Qs[qoff4(ra + a, k4)];
#pragma unroll
            for (int b2 = 0; b2 < 8; ++b2) qb[b2] = *(const float4*)&Qs[qoff4(rb + b2, k4)];
#pragma unroll
            for (int a = 0; a < 8; ++a)
#pragma unroll
                for (int b2 = 0; b2 < 8; ++b2) {
                    acc[a][b2] = fmaf(qa[a].x, qb[b2].x, acc[a][b2]);
                    acc[a][b2] = fmaf(qa[a].y, qb[b2].y, acc[a][b2]);
                    acc[a][b2] = fmaf(qa[a].z, qb[b2].z, acc[a][b2]);
                    acc[a][b2] = fmaf(qa[a].w, qb[b2].w, acc[a][b2]);
                }
        }
    } else {
        // S_col[w][v] = sum_h Q[h][w] * Q[h][v]; w = ra+a, v = rb+b
        for (int h = 0; h < 128; ++h) {
            float4 w0 = *(const float4*)&Qs[qoff4(h, 2 * ti)];
            float4 w1 = *(const float4*)&Qs[qoff4(h, 2 * ti + 1)];
            float4 v0 = *(const float4*)&Qs[qoff4(h, 2 * tj)];
            float4 v1 = *(const float4*)&Qs[qoff4(h, 2 * tj + 1)];
            float qa[8] = {w0.x, w0.y, w0.z, w0.w, w1.x, w1.y, w1.z, w1.w};
            float qb[8] = {v0.x, v0.y, v0.z, v0.w, v1.x, v1.y, v1.z, v1.w};
#pragma unroll
            for (int a = 0; a < 8; ++a)
#pragma unroll
                for (int b2 = 0; b2 < 8; ++b2)
                    acc[a][b2] = fmaf(qa[a], qb[b2], acc[a][b2]);
        }
    }

    // ---- scale + softmax over the b-dimension (distributed across tj) ----
#pragma unroll
    for (int a = 0; a < 8; ++a)
#pragma unroll
        for (int b2 = 0; b2 < 8; ++b2) acc[a][b2] *= scale;

    float rmax[8], rsum[8];
#pragma unroll
    for (int a = 0; a < 8; ++a) {
        float m = acc[a][0];
#pragma unroll
        for (int b2 = 1; b2 < 8; ++b2) m = fmaxf(m, acc[a][b2]);
        rmax[a] = m;
    }
#pragma unroll
    for (int msk = 1; msk < 16; msk <<= 1)
#pragma unroll
        for (int a = 0; a < 8; ++a)
            rmax[a] = fmaxf(rmax[a], __shfl_xor(rmax[a], msk, 64));
#pragma unroll
    for (int a = 0; a < 8; ++a) {
        float s_ = 0.f;
#pragma unroll
        for (int b2 = 0; b2 < 8; ++b2) {
            acc[a][b2] = __expf(acc[a][b2] - rmax[a]);
            s_ += acc[a][b2];
        }
        rsum[a] = s_;
    }
#pragma unroll
    for (int msk = 1; msk < 16; msk <<= 1)
#pragma unroll
        for (int a = 0; a < 8; ++a)
            rsum[a] += __shfl_xor(rsum[a], msk, 64);

    __hip_bfloat16* Abuf = (grp == 0) ? Ar : Ac;
#pragma unroll
    for (int a = 0; a < 8; ++a) {
        float inv = 1.f / rsum[a];
        int r = ra + a;
#pragma unroll
        for (int b2 = 0; b2 < 8; b2 += 2) {
            __hip_bfloat162 pk;
            pk.x = __float2bfloat16(acc[a][b2] * inv);
            pk.y = __float2bfloat16(acc[a][b2 + 1] * inv);
            *(__hip_bfloat162*)&Abuf[r * AST + rb + b2] = pk;
        }
    }
    __syncthreads();

    // ---- second matmul ----
#pragma unroll
    for (int a = 0; a < 8; ++a)
#pragma unroll
        for (int b2 = 0; b2 < 8; ++b2) acc[a][b2] = 0.f;

    if (grp == 0) {
        // X_row[h][w] = sum_g Ar[h][g] * Q[g][w]; h = ra+a, w = rb+b
        for (int g = 0; g < 128; ++g) {
            float av[8];
#pragma unroll
            for (int a = 0; a < 8; ++a)
                av[a] = __bfloat162float(Ar[(ra + a) * AST + g]);
            float4 q0 = *(const float4*)&Qs[qoff4(g, 2 * tj)];
            float4 q1 = *(const float4*)&Qs[qoff4(g, 2 * tj + 1)];
            float qv[8] = {q0.x, q0.y, q0.z, q0.w, q1.x, q1.y, q1.z, q1.w};
#pragma unroll
            for (int a = 0; a < 8; ++a)
#pragma unroll
                for (int b2 = 0; b2 < 8; ++b2)
                    acc[a][b2] = fmaf(av[a], qv[b2], acc[a][b2]);
        }
        float* Xg = xrow + plane * (size_t)HWp;
#pragma unroll
        for (int a = 0; a < 8; ++a) {
            int h = ra + a;
#pragma unroll
            for (int b2 = 0; b2 < 8; b2 += 4) {
                float4 v;
                v.x = acc[a][b2 + 0]; v.y = acc[a][b2 + 1];
                v.z = acc[a][b2 + 2]; v.w = acc[a][b2 + 3];
                *(float4*)&Xg[h * Ww + rb + b2] = v;
            }
        }
    } else {
        // X_col[w][h] = sum_v Ac[w][v] * Q[h][v]; w = ra+a, h = rb+b
        for (int v = 0; v < 128; ++v) {
            float av[8], qv[8];
#pragma unroll
            for (int a = 0; a < 8; ++a)
                av[a] = __bfloat162float(Ac[(ra + a) * AST + v]);
#pragma unroll
            for (int b2 = 0; b2 < 8; ++b2)
                qv[b2] = Qs[qoff1(rb + b2, v)];
#pragma unroll
            for (int a = 0; a < 8; ++a)
#pragma unroll
                for (int b2 = 0; b2 < 8; ++b2)
                    acc[a][b2] = fmaf(av[a], qv[b2], acc[a][b2]);
        }
        float* Xg = xcol + plane * (size_t)HWp;   // plane layout [w][h]
#pragma unroll
        for (int a = 0; a < 8; ++a) {
            int wq = ra + a;
#pragma unroll
            for (int b2 = 0; b2 < 8; b2 += 4) {
                float4 v;
                v.x = acc[a][b2 + 0]; v.y = acc[a][b2 + 1];
                v.z = acc[a][b2 + 2]; v.w = acc[a][b2 + 3];
                *(float4*)&Xg[wq * Hh + rb + b2] = v;
            }
        }
    }
}

// ======== Kernel 4: 7x7 depthwise on both branches + residual combine ========
// out[b,c,h,w] = x + dw(zrow)[h,w] + dw(zcol)[w,h] + 2*lc_b[c]
#define ZSTR 140
__global__ __launch_bounds__(256, 2)
void k_dwc(const float* __restrict__ zrow, const float* __restrict__ zcol,
           const float* __restrict__ x1, const float* __restrict__ x2,
           const float* __restrict__ lw, const float* __restrict__ lb,
           float* __restrict__ out)
{
    __shared__ float zr[22][ZSTR];   // zrow tile rows y0-3..y0+18, cols -3..130
    __shared__ float zc[22][ZSTR];   // transposed zcol tile: zc[hc][wr]
    const int pl = blockIdx.y;             // chunk-local plane = b*128 + c
    const int c  = pl & (CC - 1);
    const int b  = pl >> 7;
    const int y0 = blockIdx.x * 16;
    const int tid = threadIdx.x;
    const float* zrp = zrow + (size_t)pl * HWp;
    const float* zcp = zcol + (size_t)pl * HWp;

    for (int e = tid; e < 22 * 134; e += 256) {
        int rr = e / 134, cc2 = e - rr * 134;
        int y = y0 - 3 + rr, x = cc2 - 3;
        zr[rr][cc2] = ((unsigned)y < 128u && (unsigned)x < 128u) ? zrp[y * Ww + x] : 0.f;
    }
    for (int e = tid; e < 134 * 22; e += 256) {
        int wr = e / 22, hc = e - wr * 22;
        int wq = wr - 3, hq = y0 - 3 + hc;
        zc[hc][wr] = ((unsigned)wq < 128u && (unsigned)hq < 128u) ? zcp[wq * Hh + hq] : 0.f;
    }
    __syncthreads();

    const int tg = tid & 15, ty = tid >> 4;   // tg: x-group, ty: row 0..15
    const int x0 = tg * 8;
    const float* wb = lw + c * 49;

    float accR[8] = {0, 0, 0, 0, 0, 0, 0, 0};
    float accC[8] = {0, 0, 0, 0, 0, 0, 0, 0};
#pragma unroll
    for (int u = 0; u < 7; ++u) {
        float rw[14], cw[14];
#pragma unroll
        for (int q = 0; q < 3; ++q) {
            float4 t1 = *(const float4*)&zr[ty + u][x0 + 4 * q];
            rw[4 * q + 0] = t1.x; rw[4 * q + 1] = t1.y;
            rw[4 * q + 2] = t1.z; rw[4 * q + 3] = t1.w;
            float4 t2 = *(const float4*)&zc[ty + u][x0 + 4 * q];
            cw[4 * q + 0] = t2.x; cw[4 * q + 1] = t2.y;
            cw[4 * q + 2] = t2.z; cw[4 * q + 3] = t2.w;
        }
        float2 e1 = *(const float2*)&zr[ty + u][x0 + 12]; rw[12] = e1.x; rw[13] = e1.y;
        float2 e2 = *(const float2*)&zc[ty + u][x0 + 12]; cw[12] = e2.x; cw[13] = e2.y;
#pragma unroll
        for (int v = 0; v < 7; ++v) {
            float wr_ = wb[u * 7 + v];   // row branch:  lc[u][v]
            float wc_ = wb[v * 7 + u];   // colT branch: lc[v][u]
#pragma unroll
            for (int o = 0; o < 8; ++o) {
                accR[o] = fmaf(wr_, rw[o + v], accR[o]);
                accC[o] = fmaf(wc_, cw[o + v], accC[o]);
            }
        }
    }
    const int h = y0 + ty;
    const float* xin = (c < 64) ? (x1 + ((size_t)b * 64 + c) * HWp)
                                : (x2 + ((size_t)b * 64 + (c - 64)) * HWp);
    const float b2 = 2.f * lb[c];
    float* po = out + (size_t)pl * HWp + h * Ww + x0;
    const float* pxi = xin + h * Ww + x0;
#pragma unroll
    for (int o = 0; o < 8; o += 4) {
        float4 xv = *(const float4*)&pxi[o];
        float4 ov;
        ov.x = xv.x + accR[o + 0] + accC[o + 0] + b2;
        ov.y = xv.y + accR[o + 1] + accC[o + 1] + b2;
        ov.z = xv.z + accR[o + 2] + accC[o + 2] + b2;
        ov.w = xv.w + accR[o + 3] + accC[o + 3] + b2;
        *(float4*)&po[o] = ov;
    }
}

// ============================== launcher =====================================
extern "C" void kernel_launch(void* const* d_in, const int* in_sizes, int n_in,
                              void* d_out, int out_size, void* d_ws, size_t ws_size,
                              hipStream_t stream)
{
    const float* x1   = (const float*)d_in[0];
    const float* x2   = (const float*)d_in[1];
    const float* c_w  = (const float*)d_in[2];
    const float* c_b  = (const float*)d_in[3];
    const float* sc_w = (const float*)d_in[4];
    const float* sc_b = (const float*)d_in[5];
    const float* lc_w = (const float*)d_in[6];
    const float* lc_b = (const float*)d_in[7];
    float* out = (float*)d_out;

    // allow >64KB dynamic LDS for the attention kernel (idempotent host call)
    hipFuncSetAttribute(reinterpret_cast<const void*>(k_attn),
                        hipFuncAttributeMaxDynamicSharedMemorySize, SMEM_ATTN);

    // batch-chunked pipeline through 3 workspace slabs of nb*C*HW floats each
    const size_t perBatch = 3ull * CC * HWp * sizeof(float);  // ~25.2 MB
    int nb = (int)(ws_size / perBatch);
    if (nb < 1) nb = 1;
    if (nb > BTOT) nb = BTOT;
    const size_t slab = (size_t)nb * CC * HWp;
    float* f0 = (float*)d_ws;
    float* f1 = f0 + slab;
    float* f2 = f1 + slab;

    for (int b0 = 0; b0 < BTOT; b0 += nb) {
        int nbc = BTOT - b0; if (nbc > nb) nbc = nb;
        int npix = nbc * HWp;
        int planes = nbc * CC;
        const float* x1c = x1 + (size_t)b0 * 64 * HWp;
        const float* x2c = x2 + (size_t)b0 * 64 * HWp;

        // 1) qkv = c_w @ concat(x1,x2) + c_b      -> f0
        k_qkv<<<npix / 256, 256, 0, stream>>>(x1c, x2c, c_w, c_b, f0, npix);
        // 2) dual axial attention                 f0 -> f1 (row), f2 (col [w][h])
        k_attn<<<planes, 512, SMEM_ATTN, stream>>>(f0, f1, f2);
        // 3) second 1x1 conv on both branches     f1 -> f0, f2 -> f1
        k_c1<<<npix / 256, 256, 0, stream>>>(f1, sc_w, sc_b, f0, npix);
        k_c1<<<npix / 256, 256, 0, stream>>>(f2, sc_w, sc_b, f1, npix);
        // 4) depthwise 7x7 on both + residual     -> out
        k_dwc<<<dim3(8, planes), 256, 0, stream>>>(f0, f1, x1c, x2c, lc_w, lc_b,
                                                   out + (size_t)b0 * CC * HWp);
    }
}

// Round 3
// 1407.065 us; speedup vs baseline: 1.8093x; 1.8093x over previous
//
#include <hip/hip_runtime.h>

// Shapes (fixed by the problem)
#define CC    128          // channels
#define Hh    128
#define Ww    128
#define HWp   16384        // H*W
#define BTOT  16           // batches

// Attention LDS: Qs 128x128 fp32 swizzled (64KB) + Ar/Ac bf16 [128][AST]
// AST=138: rows 4B-aligned (even), row-stride 69 words -> 8*69=552 ≡ 24 mod 32
// -> grp1-phase2 row reads (rows 8*tj+b2) are 4-way, not 8/16-way.
#define AST   138
#define SMEM_ATTN (65536 + 2 * (CC * AST * 2))   // 136192 B

using bf16x8 = __attribute__((ext_vector_type(8))) short;
using f32x4  = __attribute__((ext_vector_type(4))) float;

__device__ __forceinline__ short f2bf(float f) {   // RNE float->bf16 (finite data)
    union { float f; unsigned u; } c; c.f = f;
    return (short)((c.u + 0x7fffu + ((c.u >> 16) & 1u)) >> 16);
}
__device__ __forceinline__ float b2f(unsigned short u) {
    union { unsigned u; float f; } c; c.u = ((unsigned)u) << 16; return c.f;
}
__device__ __forceinline__ bf16x8 pack8(const float* f) {
    bf16x8 r;
    r[0] = f2bf(f[0]); r[1] = f2bf(f[1]); r[2] = f2bf(f[2]); r[3] = f2bf(f[3]);
    r[4] = f2bf(f[4]); r[5] = f2bf(f[5]); r[6] = f2bf(f[6]); r[7] = f2bf(f[7]);
    return r;
}

// -------- Q LDS swizzle helpers (float index into Qs) --------
__device__ __forceinline__ int qoff4(int r, int c4) {
    return (r << 7) + ((c4 ^ ((r >> 3) & 7)) << 2);
}

// ============ Kernel 1: qkv = c_w @ concat(x1,x2) + c_b  (MFMA bf16) =========
// Block: 256 thr = 4 waves; block tile o=128 x p=64; wave tile o=64 x p=32.
// A (weights) hoisted to VGPR bf16 frags; B (x) loaded strided + cvt.
// MFMA 16x16x32: A lane: i=l&15, k=8*(l>>4)+j ; B lane: j=l&15, same k.
// D lane: col=l&15, row=4*(l>>4)+reg  [verified m89/m91].
__global__ __launch_bounds__(256, 2)
void k_qkv_mm(const float* __restrict__ x1, const float* __restrict__ x2,
              const float* __restrict__ w, const float* __restrict__ bias,
              float* __restrict__ out)
{
    const int tid = threadIdx.x;
    const int wv  = tid >> 6;
    const int l   = tid & 63;
    const int l15 = l & 15, lk = l >> 4;
    const int orow = (wv >> 1) * 64;
    const int pb   = blockIdx.x * 64 + (wv & 1) * 32;

    bf16x8 a[4][4];
#pragma unroll
    for (int m = 0; m < 4; ++m)
#pragma unroll
        for (int kf = 0; kf < 4; ++kf) {
            float tmp[8];
            const float* wp = &w[(size_t)(orow + 16 * m + l15) * CC + 32 * kf + 8 * lk];
            *(float4*)&tmp[0] = *(const float4*)wp;
            *(float4*)&tmp[4] = *(const float4*)(wp + 4);
            a[m][kf] = pack8(tmp);
        }

    f32x4 acc[4][2];
#pragma unroll
    for (int m = 0; m < 4; ++m)
#pragma unroll
        for (int n = 0; n < 2; ++n)
#pragma unroll
            for (int r = 0; r < 4; ++r) acc[m][n][r] = 0.f;

    const int p0 = pb + l15;
    const int b0 = p0 >> 14, s0 = p0 & (HWp - 1);
    const int p1 = p0 + 16;
    const int b1 = p1 >> 14, s1 = p1 & (HWp - 1);

#pragma unroll
    for (int kf = 0; kf < 4; ++kf) {
        const float* xb = (kf < 2) ? x1 : x2;
        const int cb = 32 * kf + 8 * lk - ((kf < 2) ? 0 : 64);
        bf16x8 bfr[2];
#pragma unroll
        for (int n = 0; n < 2; ++n) {
            const size_t base = ((size_t)(n ? b1 : b0) * 64 + cb) * HWp + (n ? s1 : s0);
            float f[8];
#pragma unroll
            for (int j = 0; j < 8; ++j) f[j] = xb[base + (size_t)j * HWp];
            bfr[n] = pack8(f);
        }
#pragma unroll
        for (int m = 0; m < 4; ++m)
#pragma unroll
            for (int n = 0; n < 2; ++n)
                acc[m][n] = __builtin_amdgcn_mfma_f32_16x16x32_bf16(
                    a[m][kf], bfr[n], acc[m][n], 0, 0, 0);
    }

#pragma unroll
    for (int m = 0; m < 4; ++m)
#pragma unroll
        for (int n = 0; n < 2; ++n) {
            const int o  = orow + 16 * m + 4 * lk;
            const int bb = n ? b1 : b0, ss = n ? s1 : s0;
#pragma unroll
            for (int r = 0; r < 4; ++r)
                out[((size_t)bb * CC + o + r) * HWp + ss] = acc[m][n][r] + bias[o + r];
        }
}

// ======= Kernel 3: z = sc_w @ v + sc_b (MFMA bf16, bf16 in / bf16 out) =======
__global__ __launch_bounds__(256, 2)
void k_sc_mm(const unsigned short* __restrict__ zin, const float* __restrict__ w,
             const float* __restrict__ bias, unsigned short* __restrict__ zout)
{
    const int tid = threadIdx.x;
    const int wv  = tid >> 6;
    const int l   = tid & 63;
    const int l15 = l & 15, lk = l >> 4;
    const int orow = (wv >> 1) * 64;
    const int pb   = blockIdx.x * 64 + (wv & 1) * 32;

    bf16x8 a[4][4];
#pragma unroll
    for (int m = 0; m < 4; ++m)
#pragma unroll
        for (int kf = 0; kf < 4; ++kf) {
            float tmp[8];
            const float* wp = &w[(size_t)(orow + 16 * m + l15) * CC + 32 * kf + 8 * lk];
            *(float4*)&tmp[0] = *(const float4*)wp;
            *(float4*)&tmp[4] = *(const float4*)(wp + 4);
            a[m][kf] = pack8(tmp);
        }

    f32x4 acc[4][2];
#pragma unroll
    for (int m = 0; m < 4; ++m)
#pragma unroll
        for (int n = 0; n < 2; ++n)
#pragma unroll
            for (int r = 0; r < 4; ++r) acc[m][n][r] = 0.f;

    const int p0 = pb + l15;
    const int b0 = p0 >> 14, s0 = p0 & (HWp - 1);
    const int p1 = p0 + 16;
    const int b1 = p1 >> 14, s1 = p1 & (HWp - 1);

#pragma unroll
    for (int kf = 0; kf < 4; ++kf) {
        const int cb = 32 * kf + 8 * lk;
        bf16x8 bfr[2];
#pragma unroll
        for (int n = 0; n < 2; ++n) {
            const size_t base = ((size_t)(n ? b1 : b0) * CC + cb) * HWp + (n ? s1 : s0);
            bf16x8 bv;
#pragma unroll
            for (int j = 0; j < 8; ++j) bv[j] = (short)zin[base + (size_t)j * HWp];
            bfr[n] = bv;
        }
#pragma unroll
        for (int m = 0; m < 4; ++m)
#pragma unroll
            for (int n = 0; n < 2; ++n)
                acc[m][n] = __builtin_amdgcn_mfma_f32_16x16x32_bf16(
                    a[m][kf], bfr[n], acc[m][n], 0, 0, 0);
    }

#pragma unroll
    for (int m = 0; m < 4; ++m)
#pragma unroll
        for (int n = 0; n < 2; ++n) {
            const int o  = orow + 16 * m + 4 * lk;
            const int bb = n ? b1 : b0, ss = n ? s1 : s0;
#pragma unroll
            for (int r = 0; r < 4; ++r)
                zout[((size_t)bb * CC + o + r) * HWp + ss] =
                    (unsigned short)f2bf(acc[m][n][r] + bias[o + r]);
        }
}

// ================= Kernel 2: per-(b,c) dual axial attention ==================
// grp0 (waves 0-3): row attention -> xrow [h][w] bf16.
// grp1 (waves 4-7): col attention; second matmul computes X_col^T directly:
//   X_colT[h][w] = sum_v Ac[w][v] * Q[h][v]  -> xcolT [h][w] bf16.
__global__ __launch_bounds__(512, 2)
void k_attn(const float* __restrict__ qkv, unsigned short* __restrict__ xrow,
            unsigned short* __restrict__ xcolT)
{
    extern __shared__ float smem[];
    float* Qs = smem;                                   // swizzled 128x128 fp32
    unsigned short* Ar = (unsigned short*)(smem + CC * 128);
    unsigned short* Ac = Ar + CC * AST;

    const int tid = threadIdx.x;
    const size_t plane = blockIdx.x;
    const float* Qg = qkv + plane * (size_t)HWp;

    const float4* Qg4 = (const float4*)Qg;
    for (int e = tid; e < HWp / 4; e += 512) {
        int r = e >> 5, c4 = e & 31;
        *(float4*)&Qs[qoff4(r, c4)] = Qg4[e];
    }
    __syncthreads();

    const int grp = tid >> 8;
    const int t   = tid & 255;
    const int ti  = t >> 4;
    const int tj  = t & 15;
    const int ra  = ti * 8;
    const int rb  = tj * 8;
    const float scale = 0.08838834764831845f;  // 128^-0.5

    float acc[8][8];
#pragma unroll
    for (int a = 0; a < 8; ++a)
#pragma unroll
        for (int b2 = 0; b2 < 8; ++b2) acc[a][b2] = 0.f;

    if (grp == 0) {
        for (int k4 = 0; k4 < 32; ++k4) {
            float4 qa[8], qb[8];
#pragma unroll
            for (int a = 0; a < 8; ++a) qa[a] = *(const float4*)&Qs[qoff4(ra + a, k4)];
#pragma unroll
            for (int b2 = 0; b2 < 8; ++b2) qb[b2] = *(const float4*)&Qs[qoff4(rb + b2, k4)];
#pragma unroll
            for (int a = 0; a < 8; ++a)
#pragma unroll
                for (int b2 = 0; b2 < 8; ++b2) {
                    acc[a][b2] = fmaf(qa[a].x, qb[b2].x, acc[a][b2]);
                    acc[a][b2] = fmaf(qa[a].y, qb[b2].y, acc[a][b2]);
                    acc[a][b2] = fmaf(qa[a].z, qb[b2].z, acc[a][b2]);
                    acc[a][b2] = fmaf(qa[a].w, qb[b2].w, acc[a][b2]);
                }
        }
    } else {
        for (int h = 0; h < 128; ++h) {
            float4 w0 = *(const float4*)&Qs[qoff4(h, 2 * ti)];
            float4 w1 = *(const float4*)&Qs[qoff4(h, 2 * ti + 1)];
            float4 v0 = *(const float4*)&Qs[qoff4(h, 2 * tj)];
            float4 v1 = *(const float4*)&Qs[qoff4(h, 2 * tj + 1)];
            float qa[8] = {w0.x, w0.y, w0.z, w0.w, w1.x, w1.y, w1.z, w1.w};
            float qb[8] = {v0.x, v0.y, v0.z, v0.w, v1.x, v1.y, v1.z, v1.w};
#pragma unroll
            for (int a = 0; a < 8; ++a)
#pragma unroll
                for (int b2 = 0; b2 < 8; ++b2)
                    acc[a][b2] = fmaf(qa[a], qb[b2], acc[a][b2]);
        }
    }

    // scale + softmax over the tj-distributed dim
#pragma unroll
    for (int a = 0; a < 8; ++a)
#pragma unroll
        for (int b2 = 0; b2 < 8; ++b2) acc[a][b2] *= scale;

    float rmax[8], rsum[8];
#pragma unroll
    for (int a = 0; a < 8; ++a) {
        float m = acc[a][0];
#pragma unroll
        for (int b2 = 1; b2 < 8; ++b2) m = fmaxf(m, acc[a][b2]);
        rmax[a] = m;
    }
#pragma unroll
    for (int msk = 1; msk < 16; msk <<= 1)
#pragma unroll
        for (int a = 0; a < 8; ++a)
            rmax[a] = fmaxf(rmax[a], __shfl_xor(rmax[a], msk, 64));
#pragma unroll
    for (int a = 0; a < 8; ++a) {
        float s_ = 0.f;
#pragma unroll
        for (int b2 = 0; b2 < 8; ++b2) {
            acc[a][b2] = __expf(acc[a][b2] - rmax[a]);
            s_ += acc[a][b2];
        }
        rsum[a] = s_;
    }
#pragma unroll
    for (int msk = 1; msk < 16; msk <<= 1)
#pragma unroll
        for (int a = 0; a < 8; ++a)
            rsum[a] += __shfl_xor(rsum[a], msk, 64);

    unsigned short* Abuf = (grp == 0) ? Ar : Ac;
#pragma unroll
    for (int a = 0; a < 8; ++a) {
        float inv = 1.f / rsum[a];
        int r = ra + a;
#pragma unroll
        for (int b2 = 0; b2 < 8; b2 += 2) {
            unsigned pk = (unsigned)(unsigned short)f2bf(acc[a][b2] * inv) |
                          ((unsigned)(unsigned short)f2bf(acc[a][b2 + 1] * inv) << 16);
            *(unsigned*)&Abuf[r * AST + rb + b2] = pk;
        }
    }
    __syncthreads();

#pragma unroll
    for (int a = 0; a < 8; ++a)
#pragma unroll
        for (int b2 = 0; b2 < 8; ++b2) acc[a][b2] = 0.f;

    if (grp == 0) {
        // X_row[h][w] = sum_g Ar[h][g] * Q[g][w]; h = ra+a, w = rb+b2
        for (int g = 0; g < 128; ++g) {
            float av[8];
#pragma unroll
            for (int a = 0; a < 8; ++a) av[a] = b2f(Ar[(ra + a) * AST + g]);
            float4 q0 = *(const float4*)&Qs[qoff4(g, 2 * tj)];
            float4 q1 = *(const float4*)&Qs[qoff4(g, 2 * tj + 1)];
            float qv[8] = {q0.x, q0.y, q0.z, q0.w, q1.x, q1.y, q1.z, q1.w};
#pragma unroll
            for (int a = 0; a < 8; ++a)
#pragma unroll
                for (int b2 = 0; b2 < 8; ++b2)
                    acc[a][b2] = fmaf(av[a], qv[b2], acc[a][b2]);
        }
        unsigned short* Xg = xrow + plane * (size_t)HWp;
#pragma unroll
        for (int a = 0; a < 8; ++a) {
            bf16x8 ov;
#pragma unroll
            for (int b2 = 0; b2 < 8; ++b2) ov[b2] = f2bf(acc[a][b2]);
            *(bf16x8*)&Xg[(ra + a) * Ww + rb] = ov;
        }
    } else {
        // X_colT[h][w] = sum_v Ac[w][v] * Q[h][v]; h = ra+a, w = rb+b2
        // Q rows indexed by ti -> 16-lane broadcast reads; Ac rows by tj (4-way).
        for (int v4 = 0; v4 < 32; ++v4) {
            float4 qv[8];
#pragma unroll
            for (int a = 0; a < 8; ++a) qv[a] = *(const float4*)&Qs[qoff4(ra + a, v4)];
            float avv[8][4];
#pragma unroll
            for (int b2 = 0; b2 < 8; ++b2) {
                const int rbase = (rb + b2) * AST + 4 * v4;
                ushort2 u0 = *(const ushort2*)&Ac[rbase];
                ushort2 u1 = *(const ushort2*)&Ac[rbase + 2];
                avv[b2][0] = b2f(u0.x); avv[b2][1] = b2f(u0.y);
                avv[b2][2] = b2f(u1.x); avv[b2][3] = b2f(u1.y);
            }
#pragma unroll
            for (int a = 0; a < 8; ++a)
#pragma unroll
                for (int b2 = 0; b2 < 8; ++b2) {
                    acc[a][b2] = fmaf(qv[a].x, avv[b2][0], acc[a][b2]);
                    acc[a][b2] = fmaf(qv[a].y, avv[b2][1], acc[a][b2]);
                    acc[a][b2] = fmaf(qv[a].z, avv[b2][2], acc[a][b2]);
                    acc[a][b2] = fmaf(qv[a].w, avv[b2][3], acc[a][b2]);
                }
        }
        unsigned short* Xg = xcolT + plane * (size_t)HWp;
#pragma unroll
        for (int a = 0; a < 8; ++a) {
            bf16x8 ov;
#pragma unroll
            for (int b2 = 0; b2 < 8; ++b2) ov[b2] = f2bf(acc[a][b2]);
            *(bf16x8*)&Xg[(ra + a) * Ww + rb] = ov;
        }
    }
}

// ======== Kernel 4: 7x7 depthwise on both branches + residual combine ========
// Both z inputs are [h][w] planes (bf16). Col branch uses transposed weights.
#define ZSTR 140
__global__ __launch_bounds__(256, 2)
void k_dwc(const unsigned short* __restrict__ zrow,
           const unsigned short* __restrict__ zcolT,
           const float* __restrict__ x1, const float* __restrict__ x2,
           const float* __restrict__ lw, const float* __restrict__ lb,
           float* __restrict__ out)
{
    __shared__ float zr[22][ZSTR];
    __shared__ float zc[22][ZSTR];
    const int pl = blockIdx.y;
    const int c  = pl & (CC - 1);
    const int b  = pl >> 7;
    const int y0 = blockIdx.x * 16;
    const int tid = threadIdx.x;
    const unsigned short* zrp = zrow  + (size_t)pl * HWp;
    const unsigned short* zcp = zcolT + (size_t)pl * HWp;

    for (int e = tid; e < 22 * 134; e += 256) {
        int rr = e / 134, cc2 = e - rr * 134;
        int y = y0 - 3 + rr, x = cc2 - 3;
        bool ok = ((unsigned)y < 128u) & ((unsigned)x < 128u);
        zr[rr][cc2] = ok ? b2f(zrp[y * Ww + x]) : 0.f;
        zc[rr][cc2] = ok ? b2f(zcp[y * Ww + x]) : 0.f;
    }
    __syncthreads();

    const int tg = tid & 15, ty = tid >> 4;
    const int x0 = tg * 8;
    const float* wb = lw + c * 49;

    float accR[8] = {0, 0, 0, 0, 0, 0, 0, 0};
    float accC[8] = {0, 0, 0, 0, 0, 0, 0, 0};
#pragma unroll
    for (int u = 0; u < 7; ++u) {
        float rw[14], cw[14];
#pragma unroll
        for (int q = 0; q < 3; ++q) {
            float4 t1 = *(const float4*)&zr[ty + u][x0 + 4 * q];
            rw[4 * q + 0] = t1.x; rw[4 * q + 1] = t1.y;
            rw[4 * q + 2] = t1.z; rw[4 * q + 3] = t1.w;
            float4 t2 = *(const float4*)&zc[ty + u][x0 + 4 * q];
            cw[4 * q + 0] = t2.x; cw[4 * q + 1] = t2.y;
            cw[4 * q + 2] = t2.z; cw[4 * q + 3] = t2.w;
        }
        float2 e1 = *(const float2*)&zr[ty + u][x0 + 12]; rw[12] = e1.x; rw[13] = e1.y;
        float2 e2 = *(const float2*)&zc[ty + u][x0 + 12]; cw[12] = e2.x; cw[13] = e2.y;
#pragma unroll
        for (int v = 0; v < 7; ++v) {
            float wr_ = wb[u * 7 + v];   // row branch:  lc[u][v]
            float wc_ = wb[v * 7 + u];   // colT branch: lc[v][u]
#pragma unroll
            for (int o = 0; o < 8; ++o) {
                accR[o] = fmaf(wr_, rw[o + v], accR[o]);
                accC[o] = fmaf(wc_, cw[o + v], accC[o]);
            }
        }
    }
    const int h = y0 + ty;
    const float* xin = (c < 64) ? (x1 + ((size_t)b * 64 + c) * HWp)
                                : (x2 + ((size_t)b * 64 + (c - 64)) * HWp);
    const float b2 = 2.f * lb[c];
    float* po = out + (size_t)pl * HWp + h * Ww + x0;
    const float* pxi = xin + h * Ww + x0;
#pragma unroll
    for (int o = 0; o < 8; o += 4) {
        float4 xv = *(const float4*)&pxi[o];
        float4 ov;
        ov.x = xv.x + accR[o + 0] + accC[o + 0] + b2;
        ov.y = xv.y + accR[o + 1] + accC[o + 1] + b2;
        ov.z = xv.z + accR[o + 2] + accC[o + 2] + b2;
        ov.w = xv.w + accR[o + 3] + accC[o + 3] + b2;
        *(float4*)&po[o] = ov;
    }
}

// ============================== launcher =====================================
extern "C" void kernel_launch(void* const* d_in, const int* in_sizes, int n_in,
                              void* d_out, int out_size, void* d_ws, size_t ws_size,
                              hipStream_t stream)
{
    const float* x1   = (const float*)d_in[0];
    const float* x2   = (const float*)d_in[1];
    const float* c_w  = (const float*)d_in[2];
    const float* c_b  = (const float*)d_in[3];
    const float* sc_w = (const float*)d_in[4];
    const float* sc_b = (const float*)d_in[5];
    const float* lc_w = (const float*)d_in[6];
    const float* lc_b = (const float*)d_in[7];
    float* out = (float*)d_out;

    hipFuncSetAttribute(reinterpret_cast<const void*>(k_attn),
                        hipFuncAttributeMaxDynamicSharedMemorySize, SMEM_ATTN);

    // ws per batch: qkv fp32 (8MB) + xrow bf16 (4MB) + xcolT bf16 (4MB).
    // z0/z1 (bf16) overlay the dead qkv slab.
    const size_t perBatch = (size_t)CC * HWp * 8;   // 16.78 MB
    int nb = (int)(ws_size / perBatch);
    if (nb < 1) nb = 1;
    if (nb > BTOT) nb = BTOT;
    const size_t slabE = (size_t)nb * CC * HWp;     // elements per slab
    float* f0 = (float*)d_ws;                                 // qkv fp32
    unsigned short* f1 = (unsigned short*)(f0 + slabE);       // xrow bf16
    unsigned short* f2 = f1 + slabE;                          // xcolT bf16
    unsigned short* z0 = (unsigned short*)f0;                 // overlay
    unsigned short* z1 = z0 + slabE;

    for (int b0 = 0; b0 < BTOT; b0 += nb) {
        int nbc = BTOT - b0; if (nbc > nb) nbc = nb;
        int npix = nbc * HWp;
        int planes = nbc * CC;
        const float* x1c = x1 + (size_t)b0 * 64 * HWp;
        const float* x2c = x2 + (size_t)b0 * 64 * HWp;

        // 1) qkv (MFMA)                    -> f0 (fp32)
        k_qkv_mm<<<npix / 64, 256, 0, stream>>>(x1c, x2c, c_w, c_b, f0);
        // 2) dual axial attention          f0 -> f1 (xrow), f2 (xcolT), both [h][w] bf16
        k_attn<<<planes, 512, SMEM_ATTN, stream>>>(f0, f1, f2);
        // 3) sc conv on both branches (MFMA)   f1 -> z0, f2 -> z1 (bf16)
        k_sc_mm<<<npix / 64, 256, 0, stream>>>(f1, sc_w, sc_b, z0);
        k_sc_mm<<<npix / 64, 256, 0, stream>>>(f2, sc_w, sc_b, z1);
        // 4) depthwise 7x7 both branches + residual -> out
        k_dwc<<<dim3(8, planes), 256, 0, stream>>>(z0, z1, x1c, x2c, lc_w, lc_b,
                                                   out + (size_t)b0 * CC * HWp);
    }
}